// Round 9
// baseline (3248.716 us; speedup 1.0000x reference)
//
#include <hip/hip_runtime.h>
#include <hip/hip_fp16.h>

typedef _Float16 half8 __attribute__((ext_vector_type(8)));
typedef float floatx4 __attribute__((ext_vector_type(4)));
typedef unsigned int uintx4 __attribute__((ext_vector_type(4)));

#define INPUT  512
#define HIDDEN 1024
#define OUTPUT 256
#define BATCH  128
#define SEQ    512

// ---------------------------------------------------------------------------
// K0: transpose + fp32->fp16:  W_h [K][N] f32 -> WhT [N][K] f16
// ---------------------------------------------------------------------------
__global__ __launch_bounds__(256) void transpose_f32_to_f16(
    const float* __restrict__ in, _Float16* __restrict__ out, int K, int N) {
  __shared__ float tile[32][33];
  int bi = blockIdx.x;
  int bj = blockIdx.y;
  int cc = threadIdx.x & 31;
  int rr = threadIdx.x >> 5;
#pragma unroll
  for (int s = 0; s < 4; ++s) {
    int r = rr + 8 * s;
    tile[r][cc] = in[(size_t)(bi * 32 + r) * N + bj * 32 + cc];
  }
  __syncthreads();
#pragma unroll
  for (int s = 0; s < 4; ++s) {
    int nl = rr + 8 * s;
    out[(size_t)(bj * 32 + nl) * K + bi * 32 + cc] = (_Float16)tile[cc][nl];
  }
}

// ---------------------------------------------------------------------------
// K0b: pack W_in [512][1024] f32 into MFMA B-fragment order (fp16).
// ---------------------------------------------------------------------------
__global__ __launch_bounds__(256) void pack_win(
    const float* __restrict__ W, _Float16* __restrict__ P) {
  int idx = blockIdx.x * 256 + threadIdx.x;   // 0..524287
  int k = idx >> 10, n = idx & 1023;
  P[((size_t)(k >> 5) << 15) + (n << 5) + (k & 31)] = (_Float16)W[idx];
}

// ---------------------------------------------------------------------------
// K1: xin[S][B][H] = x @ W_in  (time-major). 64x128 tile, 4 waves,
// 8 ntiles/wave, packed-fragment B loads.  (validated, R6/R7)
// ---------------------------------------------------------------------------
__global__ __launch_bounds__(256) void xin_gemm(
    const float* __restrict__ x, const _Float16* __restrict__ WinP,
    _Float16* __restrict__ xin) {
  int bid = blockIdx.x;                     // 8192 blocks
  int bm = (bid & 7) * 128 + ((bid >> 3) & 127);   // 0..1023
  int bn = bid >> 10;                       // 0..7
  int tid = threadIdx.x;
  int l = tid & 63;
  int w = tid >> 6;
  int l15 = l & 15;
  int lk = (l >> 4) << 3;

  int rowbase = bm * 64 + w * 16;
  int colbase = bn * 128;

  floatx4 acc[8];
#pragma unroll
  for (int nt = 0; nt < 8; ++nt) acc[nt] = (floatx4){0.f, 0.f, 0.f, 0.f};

  const float* xrow = x + (size_t)(rowbase + l15) * INPUT;

  for (int k0 = 0; k0 < INPUT; k0 += 32) {
    int ak = k0 + lk;
    float4 xa = *reinterpret_cast<const float4*>(xrow + ak);
    float4 xb = *reinterpret_cast<const float4*>(xrow + ak + 4);
    half8 a;
    a[0] = (_Float16)xa.x; a[1] = (_Float16)xa.y;
    a[2] = (_Float16)xa.z; a[3] = (_Float16)xa.w;
    a[4] = (_Float16)xb.x; a[5] = (_Float16)xb.y;
    a[6] = (_Float16)xb.z; a[7] = (_Float16)xb.w;
    const _Float16* pq = WinP + ((size_t)(k0 >> 5) << 15) + l15 * 32 + lk;
#pragma unroll
    for (int nt = 0; nt < 8; ++nt) {
      half8 b = *reinterpret_cast<const half8*>(pq + (colbase + nt * 16) * 32);
      acc[nt] = __builtin_amdgcn_mfma_f32_16x16x32_f16(a, b, acc[nt], 0, 0, 0);
    }
  }

  int orow = rowbase + ((l >> 4) << 2);
#pragma unroll
  for (int nt = 0; nt < 8; ++nt)
#pragma unroll
    for (int i = 0; i < 4; ++i) {
      int r = orow + i;
      int b = r >> 9;
      int s = r & 511;
      xin[((size_t)s * BATCH + b) * HIDDEN + colbase + nt * 16 + l15] =
          (_Float16)acc[nt][i];
    }
}

// ---------------------------------------------------------------------------
// K2: persistent recurrence — R7 skeleton (proven), 4-wave A-reuse variant.
// 128 blocks = 8 batch-groups (16 rows, -> XCD m) x 16 N-slices (64 cols).
// 256 threads = 4 waves = 2 col-pairs (p) x 2 K-halves (kg).  Each wave
// holds TWO ntiles' W_h (128 VGPR) and reuses every staged A-fragment for
// 2 MFMAs -> LDS A-read traffic halves vs R7 (64 reads/step, was 128).
// Exchange hbuf layout W(row,col) = (col>>2)*64 + row*4 + (col&3): each
// consumer thread's poll set = ONE contiguous 256B run -> 16 dwordx4 from a
// single address with imm offsets, fused issue+wait (R5 lesson); selective
// per-slab retry re-reads only stale slabs.  Tagged words, agent-scope
// stores, direct data polling (R2/R4/R7 proven semantics).
// ---------------------------------------------------------------------------
__global__ __launch_bounds__(256) void liquid_scan(
    const _Float16* __restrict__ xin,   // [S][B][H]
    const _Float16* __restrict__ WhT,   // [H n][H k]
    const float* __restrict__ b_in, const float* __restrict__ b_h,
    const float* __restrict__ tau,
    unsigned int* hbuf,                 // [2][8][16384] tagged u32, memset-0
    float* __restrict__ hfinal) {       // [B][H] f32
  int blk = blockIdx.x;
  int m = blk & 7;                  // batch group -> XCD m (perf heuristic)
  int j = blk >> 3;                 // N slice, 0..15 (64 cols)
  int tid = threadIdx.x;            // 0..255
  int l = tid & 63;
  int w = tid >> 6;                 // 0..3
  int p = w & 1;                    // col-pair
  int kg = w >> 1;                  // K half
  int l15 = l & 15;
  int hi = l >> 4;                  // 0..3
  int lk = hi << 3;

  __shared__ _Float16 Ald[16][1032];   // h_t tile (R7 proven layout)
  __shared__ float part[2][2][4][64];  // [p][dest kg][i][lane]

  // ---- stationary W_h: two ntiles per wave (128 VGPR) ----
  half8 wf0[16], wf1[16];
  {
    const _Float16* wb0 =
        WhT + (size_t)(j * 64 + p * 32 + l15) * HIDDEN + kg * 512 + lk;
    const _Float16* wb1 = wb0 + 16 * HIDDEN;
#pragma unroll
    for (int q = 0; q < 16; ++q) {
      wf0[q] = *reinterpret_cast<const half8*>(wb0 + q * 32);
      wf1[q] = *reinterpret_cast<const half8*>(wb1 + q * 32);
    }
  }

  // wave's finalize cols: c = j*64 + p*32 + kg*16 + l15; rows 4hi+i
  const int c = j * 64 + p * 32 + kg * 16 + l15;
  const float bias_c = b_in[c] + b_h[c];
  const float invtau_c = 1.0f / tau[c];
  float hown[4] = {0.f, 0.f, 0.f, 0.f};
  const int gb0 = m * 16 + hi * 4;        // global batch row base (+i)
  // producer store position (row bloc=4hi+i, col c):
  const int Wbase = (c >> 2) * 64 + (c & 3);   // + bloc*4

  // ---- xin 2-deep pipeline: rows gb0..gb0+3, col c ----
  _Float16 xc[4], x1[4], xn[4];
#pragma unroll
  for (int i = 0; i < 4; ++i) {
    xc[i] = xin[((size_t)0 * BATCH + gb0 + i) * HIDDEN + c];
    x1[i] = xin[((size_t)1 * BATCH + gb0 + i) * HIDDEN + c];
  }

  for (int t = 0; t < SEQ; ++t) {
    if (t > 0) {
      // poll: thread's 64 words are contiguous at bp (256B)
      unsigned int* bp =
          hbuf + (size_t)(t & 1) * 131072 + m * 16384 + tid * 64;
      const unsigned want = (unsigned)t;
      uintx4 q0, q1, q2, q3, q4, q5, q6, q7, q8, q9, qa, qb, qc, qd, qe, qf;
      // full round: fused issue+wait (no load outlives its asm block)
      asm volatile(
          "global_load_dwordx4 %0, %16, off sc1\n\t"
          "global_load_dwordx4 %1, %16, off offset:16 sc1\n\t"
          "global_load_dwordx4 %2, %16, off offset:32 sc1\n\t"
          "global_load_dwordx4 %3, %16, off offset:48 sc1\n\t"
          "global_load_dwordx4 %4, %16, off offset:64 sc1\n\t"
          "global_load_dwordx4 %5, %16, off offset:80 sc1\n\t"
          "global_load_dwordx4 %6, %16, off offset:96 sc1\n\t"
          "global_load_dwordx4 %7, %16, off offset:112 sc1\n\t"
          "global_load_dwordx4 %8, %16, off offset:128 sc1\n\t"
          "global_load_dwordx4 %9, %16, off offset:144 sc1\n\t"
          "global_load_dwordx4 %10, %16, off offset:160 sc1\n\t"
          "global_load_dwordx4 %11, %16, off offset:176 sc1\n\t"
          "global_load_dwordx4 %12, %16, off offset:192 sc1\n\t"
          "global_load_dwordx4 %13, %16, off offset:208 sc1\n\t"
          "global_load_dwordx4 %14, %16, off offset:224 sc1\n\t"
          "global_load_dwordx4 %15, %16, off offset:240 sc1\n\t"
          "s_waitcnt vmcnt(0)"
          : "=&v"(q0), "=&v"(q1), "=&v"(q2), "=&v"(q3), "=&v"(q4),
            "=&v"(q5), "=&v"(q6), "=&v"(q7), "=&v"(q8), "=&v"(q9),
            "=&v"(qa), "=&v"(qb), "=&v"(qc), "=&v"(qd), "=&v"(qe),
            "=&v"(qf)
          : "v"(bp)
          : "memory");
      unsigned need = 0u;
#define CHK(Q, I)                                                         \
      {                                                                   \
        unsigned bad = ((Q[0] ^ want) | (Q[1] ^ want) | (Q[2] ^ want) |   \
                        (Q[3] ^ want)) & 0xFFFFu;                         \
        if (__any(bad != 0u)) need |= (1u << I);                          \
      }
      CHK(q0, 0) CHK(q1, 1) CHK(q2, 2) CHK(q3, 3) CHK(q4, 4) CHK(q5, 5)
      CHK(q6, 6) CHK(q7, 7) CHK(q8, 8) CHK(q9, 9) CHK(qa, 10) CHK(qb, 11)
      CHK(qc, 12) CHK(qd, 13) CHK(qe, 14) CHK(qf, 15)
      // selective retry: reload only stale slabs (1 load each)
      while (need) {
#define RETRY(Q, I, OFF)                                                  \
        if (need & (1u << I)) {                                           \
          asm volatile("global_load_dwordx4 %0, %1, off offset:" #OFF     \
                       " sc1\n\ts_waitcnt vmcnt(0)"                       \
                       : "=&v"(Q) : "v"(bp) : "memory");                  \
          unsigned bad = ((Q[0] ^ want) | (Q[1] ^ want) | (Q[2] ^ want) | \
                          (Q[3] ^ want)) & 0xFFFFu;                       \
          if (!__any(bad != 0u)) need &= ~(1u << I);                      \
        }
        RETRY(q0, 0, 0) RETRY(q1, 1, 16) RETRY(q2, 2, 32) RETRY(q3, 3, 48)
        RETRY(q4, 4, 64) RETRY(q5, 5, 80) RETRY(q6, 6, 96) RETRY(q7, 7, 112)
        RETRY(q8, 8, 128) RETRY(q9, 9, 144) RETRY(qa, 10, 160)
        RETRY(qb, 11, 176) RETRY(qc, 12, 192) RETRY(qd, 13, 208)
        RETRY(qe, 14, 224) RETRY(qf, 15, 240)
#undef RETRY
      }
#undef CHK
      // strip tags -> Ald[I][tid*4 .. +3]  (R7's conflict-free pattern)
#define STRIP(Q, I)                                                          \
      {                                                                      \
        unsigned lo = __builtin_amdgcn_perm(Q[1], Q[0], 0x07060302u);        \
        unsigned hi2 = __builtin_amdgcn_perm(Q[3], Q[2], 0x07060302u);       \
        unsigned int* d =                                                    \
            reinterpret_cast<unsigned int*>(&Ald[I][tid * 4]);               \
        d[0] = lo; d[1] = hi2;                                               \
      }
      STRIP(q0, 0) STRIP(q1, 1) STRIP(q2, 2) STRIP(q3, 3) STRIP(q4, 4)
      STRIP(q5, 5) STRIP(q6, 6) STRIP(q7, 7) STRIP(q8, 8) STRIP(q9, 9)
      STRIP(qa, 10) STRIP(qb, 11) STRIP(qc, 12) STRIP(qd, 13) STRIP(qe, 14)
      STRIP(qf, 15)
#undef STRIP
    }

    // xin loads for t+2 (issued here; consumed a full step later)
    {
      const int ts = (t + 2 < SEQ) ? t + 2 : SEQ - 1;
#pragma unroll
      for (int i = 0; i < 4; ++i)
        xn[i] = xin[((size_t)ts * BATCH + gb0 + i) * HIDDEN + c];
    }
    __syncthreads();  // B1: h_t staged in LDS

    floatx4 acc0 = (floatx4){0.f, 0.f, 0.f, 0.f};
    floatx4 acc1 = (floatx4){0.f, 0.f, 0.f, 0.f};
    if (t > 0) {
      const int kb = kg * 512 + lk;
#pragma unroll
      for (int q = 0; q < 16; ++q) {
        half8 a = *reinterpret_cast<const half8*>(&Ald[l15][kb + q * 32]);
        acc0 = __builtin_amdgcn_mfma_f32_16x16x32_f16(a, wf0[q], acc0, 0, 0, 0);
        acc1 = __builtin_amdgcn_mfma_f32_16x16x32_f16(a, wf1[q], acc1, 0, 0, 0);
      }
    }
    // swap the "other" ntile's partial to its finalizer wave (pair p)
    if (kg == 0) {
#pragma unroll
      for (int i = 0; i < 4; ++i) part[p][1][i][l] = acc1[i];
    } else {
#pragma unroll
      for (int i = 0; i < 4; ++i) part[p][0][i][l] = acc0[i];
    }
    __syncthreads();  // B2: partials swapped; also protects Ald WAR

    unsigned int* outb = hbuf + (size_t)((t + 1) & 1) * 131072 + m * 16384;
#pragma unroll
    for (int i = 0; i < 4; ++i) {
      const float mine = (kg == 0) ? acc0[i] : acc1[i];
      float pre = mine + part[p][kg][i][l] + (float)xc[i] + bias_c;
      pre = fminf(fmaxf(pre, -15.f), 15.f);
      const float e = __expf(2.f * pre);
      const float dx = (e - 1.f) / (e + 1.f);
      const float hn = hown[i] + (dx - hown[i]) * invtau_c;
      hown[i] = hn;
      if (t < SEQ - 1) {
        const unsigned short hb =
            __builtin_bit_cast(unsigned short, (_Float16)hn);
        const unsigned word = ((unsigned)hb << 16) | (unsigned)(t + 1);
        __hip_atomic_store(outb + Wbase + (hi * 4 + i) * 4, word,
                           __ATOMIC_RELAXED, __HIP_MEMORY_SCOPE_AGENT);
      } else {
        hfinal[(size_t)(gb0 + i) * HIDDEN + c] = hn;
      }
    }
    // rotate xin pipeline
#pragma unroll
    for (int i = 0; i < 4; ++i) { xc[i] = x1[i]; x1[i] = xn[i]; }
  }
}

// ---------------------------------------------------------------------------
// K3: out[B][256] = hfinal @ W_out + b_out
// ---------------------------------------------------------------------------
__global__ __launch_bounds__(256) void out_gemm(
    const float* __restrict__ hfinal, const float* __restrict__ Wout,
    const float* __restrict__ bout, float* __restrict__ out) {
  int b0 = blockIdx.x * 2;
  int o = threadIdx.x;
  float a0 = 0.f, a1 = 0.f;
  for (int k = 0; k < HIDDEN; ++k) {
    float wv = Wout[(size_t)k * OUTPUT + o];
    a0 += hfinal[(size_t)b0 * HIDDEN + k] * wv;
    a1 += hfinal[(size_t)(b0 + 1) * HIDDEN + k] * wv;
  }
  out[(size_t)b0 * OUTPUT + o] = a0 + bout[o];
  out[(size_t)(b0 + 1) * OUTPUT + o] = a1 + bout[o];
}

// ---------------------------------------------------------------------------
extern "C" void kernel_launch(void* const* d_in, const int* in_sizes, int n_in,
                              void* d_out, int out_size, void* d_ws,
                              size_t ws_size, hipStream_t stream) {
  const float* x     = (const float*)d_in[0];
  const float* W_in  = (const float*)d_in[1];
  const float* b_in  = (const float*)d_in[2];
  const float* W_h   = (const float*)d_in[3];
  const float* b_h   = (const float*)d_in[4];
  const float* tau   = (const float*)d_in[5];
  const float* W_out = (const float*)d_in[6];
  const float* b_out = (const float*)d_in[7];
  float* out = (float*)d_out;

  char* ws = (char*)d_ws;
  _Float16* xin = (_Float16*)ws;  ws += (size_t)BATCH * SEQ * HIDDEN * 2;  // 134MB
  _Float16* WinP = (_Float16*)ws; ws += (size_t)INPUT * HIDDEN * 2;        // 1MB
  _Float16* WhT = (_Float16*)ws;  ws += (size_t)HIDDEN * HIDDEN * 2;       // 2MB
  unsigned int* hbuf = (unsigned int*)ws;
  ws += (size_t)2 * BATCH * HIDDEN * 4;                                    // 1MB
  float* hfin = (float*)ws;       ws += (size_t)BATCH * HIDDEN * 4;        // 512KB

  // zero tags (tag 0 never polled: t=0 skips poll/MFMA since h_0 = 0)
  hipMemsetAsync(hbuf, 0, (size_t)2 * BATCH * HIDDEN * 4, stream);

  transpose_f32_to_f16<<<dim3(HIDDEN / 32, HIDDEN / 32), 256, 0, stream>>>(
      W_h, WhT, HIDDEN, HIDDEN);
  pack_win<<<(INPUT * HIDDEN) / 256, 256, 0, stream>>>(W_in, WinP);

  xin_gemm<<<(BATCH * SEQ / 64) * (HIDDEN / 128), 256, 0, stream>>>(x, WinP,
                                                                    xin);

  liquid_scan<<<128, 256, 0, stream>>>(xin, WhT, b_in, b_h, tau, hbuf, hfin);

  out_gemm<<<BATCH / 2, OUTPUT, 0, stream>>>(hfin, W_out, b_out, out);
}

// Round 10
// 1407.884 us; speedup vs baseline: 2.3075x; 2.3075x over previous
//
#include <hip/hip_runtime.h>
#include <hip/hip_fp16.h>

typedef _Float16 half8 __attribute__((ext_vector_type(8)));
typedef float floatx4 __attribute__((ext_vector_type(4)));
typedef unsigned int uintx4 __attribute__((ext_vector_type(4)));

#define INPUT  512
#define HIDDEN 1024
#define OUTPUT 256
#define BATCH  128
#define SEQ    512

// ---------------------------------------------------------------------------
// K0: transpose + fp32->fp16:  W_h [K][N] f32 -> WhT [N][K] f16
// ---------------------------------------------------------------------------
__global__ __launch_bounds__(256) void transpose_f32_to_f16(
    const float* __restrict__ in, _Float16* __restrict__ out, int K, int N) {
  __shared__ float tile[32][33];
  int bi = blockIdx.x;
  int bj = blockIdx.y;
  int cc = threadIdx.x & 31;
  int rr = threadIdx.x >> 5;
#pragma unroll
  for (int s = 0; s < 4; ++s) {
    int r = rr + 8 * s;
    tile[r][cc] = in[(size_t)(bi * 32 + r) * N + bj * 32 + cc];
  }
  __syncthreads();
#pragma unroll
  for (int s = 0; s < 4; ++s) {
    int nl = rr + 8 * s;
    out[(size_t)(bj * 32 + nl) * K + bi * 32 + cc] = (_Float16)tile[cc][nl];
  }
}

// ---------------------------------------------------------------------------
// K0b: pack W_in [512][1024] f32 into MFMA B-fragment order (fp16).
// ---------------------------------------------------------------------------
__global__ __launch_bounds__(256) void pack_win(
    const float* __restrict__ W, _Float16* __restrict__ P) {
  int idx = blockIdx.x * 256 + threadIdx.x;   // 0..524287
  int k = idx >> 10, n = idx & 1023;
  P[((size_t)(k >> 5) << 15) + (n << 5) + (k & 31)] = (_Float16)W[idx];
}

// ---------------------------------------------------------------------------
// K1: xin[S][B][H] = x @ W_in  (time-major). 64x128 tile, 4 waves,
// 8 ntiles/wave, packed-fragment B loads.  (validated, R6/R7)
// ---------------------------------------------------------------------------
__global__ __launch_bounds__(256) void xin_gemm(
    const float* __restrict__ x, const _Float16* __restrict__ WinP,
    _Float16* __restrict__ xin) {
  int bid = blockIdx.x;                     // 8192 blocks
  int bm = (bid & 7) * 128 + ((bid >> 3) & 127);   // 0..1023
  int bn = bid >> 10;                       // 0..7
  int tid = threadIdx.x;
  int l = tid & 63;
  int w = tid >> 6;
  int l15 = l & 15;
  int lk = (l >> 4) << 3;

  int rowbase = bm * 64 + w * 16;
  int colbase = bn * 128;

  floatx4 acc[8];
#pragma unroll
  for (int nt = 0; nt < 8; ++nt) acc[nt] = (floatx4){0.f, 0.f, 0.f, 0.f};

  const float* xrow = x + (size_t)(rowbase + l15) * INPUT;

  for (int k0 = 0; k0 < INPUT; k0 += 32) {
    int ak = k0 + lk;
    float4 xa = *reinterpret_cast<const float4*>(xrow + ak);
    float4 xb = *reinterpret_cast<const float4*>(xrow + ak + 4);
    half8 a;
    a[0] = (_Float16)xa.x; a[1] = (_Float16)xa.y;
    a[2] = (_Float16)xa.z; a[3] = (_Float16)xa.w;
    a[4] = (_Float16)xb.x; a[5] = (_Float16)xb.y;
    a[6] = (_Float16)xb.z; a[7] = (_Float16)xb.w;
    const _Float16* pq = WinP + ((size_t)(k0 >> 5) << 15) + l15 * 32 + lk;
#pragma unroll
    for (int nt = 0; nt < 8; ++nt) {
      half8 b = *reinterpret_cast<const half8*>(pq + (colbase + nt * 16) * 32);
      acc[nt] = __builtin_amdgcn_mfma_f32_16x16x32_f16(a, b, acc[nt], 0, 0, 0);
    }
  }

  int orow = rowbase + ((l >> 4) << 2);
#pragma unroll
  for (int nt = 0; nt < 8; ++nt)
#pragma unroll
    for (int i = 0; i < 4; ++i) {
      int r = orow + i;
      int b = r >> 9;
      int s = r & 511;
      xin[((size_t)s * BATCH + b) * HIDDEN + colbase + nt * 16 + l15] =
          (_Float16)acc[nt][i];
    }
}

// ---------------------------------------------------------------------------
// K2: persistent recurrence — R7 skeleton (proven 1112us), K-quarter split.
// 128 blocks = 8 batch-groups (16 rows, -> XCD m) x 16 N-slices (64 cols).
// 8 waves = 2 ntile-pairs (g: 32 cols) x 4 K-quarters (kg: 256 k).
// Per wave: 8 ds_read_b128 A-frags + 16 MFMA (2 ntiles' weights in 64 VGPR).
// A-read redundancy P=4 (R7) -> P=2: per-CU staged-A LDS traffic halves.
// 4-way K-partials summed via LDS: layout [g][nt2][i][lane][4kg] so the
// finalizer reads one aligned b128; writer kg-slot rotated by (l>>3) to
// break bank pile-up (sum is order-independent -> no unswizzle needed).
// Poll / STRIP / Ald / tagged row-contiguous stores / xin pipeline: R7
// verbatim (proven).  Epilogue: thread (w'=tid>>6,l'=tid&63) finalizes
// rows {2w',2w'+1} at col l' -> 256B-contiguous stores per row.
// ---------------------------------------------------------------------------
__global__ __launch_bounds__(512) void liquid_scan(
    const _Float16* __restrict__ xin,   // [S][B][H]
    const _Float16* __restrict__ WhT,   // [H n][H k]
    const float* __restrict__ b_in, const float* __restrict__ b_h,
    const float* __restrict__ tau,
    unsigned int* hbuf,                 // [2][8][16][1024] tagged u32
    float* __restrict__ hfinal) {       // [B][H] f32
  int blk = blockIdx.x;
  int m = blk & 7;                  // batch group -> XCD m (perf heuristic)
  int j = blk >> 3;                 // N slice, 0..15
  int tid = threadIdx.x;
  int l = tid & 63;
  int w = tid >> 6;                 // 0..7
  int g = w & 1;                    // ntile-pair (32 cols)
  int kg = w >> 1;                  // K quarter (256 k)
  int l15 = l & 15;
  int lk = (l >> 4) << 3;

  __shared__ _Float16 Ald[16][1032];         // h_t tile (R7 proven layout)
  __shared__ float part[2][2][4][64][4];     // [g][nt2][i][lane][kg-slot]

  // ---- stationary W_h: two ntiles x K-quarter per wave (64 VGPR) ----
  half8 wf0[8], wf1[8];
  {
    const _Float16* wb0 =
        WhT + (size_t)(j * 64 + g * 32 + l15) * HIDDEN + kg * 256 + lk;
    const _Float16* wb1 = wb0 + 16 * HIDDEN;
#pragma unroll
    for (int kt = 0; kt < 8; ++kt) {
      wf0[kt] = *reinterpret_cast<const half8*>(wb0 + kt * 32);
      wf1[kt] = *reinterpret_cast<const half8*>(wb1 + kt * 32);
    }
  }

  // ---- finalize mapping: thread -> rows {2w',2w'+1}, col l' ----
  const int wp = tid >> 6;               // w' (reuse w, but explicit)
  const int lp = tid & 63;               // l' = local col
  const int gc = j * 64 + lp;            // global col
  const float bias_c = b_in[gc] + b_h[gc];
  const float invtau_c = 1.0f / tau[gc];
  float hown[2] = {0.f, 0.f};
  const int r0 = 2 * wp;                 // local rows r0, r0+1
  const int gb0 = m * 16 + r0;           // global batch rows

  // partial-read indices for rows r0+b, col lp
  const int ntg = lp >> 5;               // g of the col
  const int nt2 = (lp >> 4) & 1;         // ntile within pair
  // lane that holds (row r, col lp) in C/D layout: ((r>>2)<<4) | (lp&15)
  const int lsrc0 = (((r0 + 0) >> 2) << 4) | (lp & 15);
  const int lsrc1 = (((r0 + 1) >> 2) << 4) | (lp & 15);
  const int i_0 = (r0 + 0) & 3;
  const int i_1 = (r0 + 1) & 3;

  // ---- poll assignment (R7 verbatim): thread's 8 slabs ----
  const int srow = tid >> 8;
  const int scol4 = (tid & 255) * 4;
  unsigned int* gbase = hbuf + m * 16384 + tid * 4;

  // ---- xin 2-deep pipeline: rows gb0, gb0+1 at col gc ----
  _Float16 xc[2], x1[2], xn[2];
#pragma unroll
  for (int b = 0; b < 2; ++b) {
    xc[b] = xin[((size_t)0 * BATCH + gb0 + b) * HIDDEN + gc];
    x1[b] = xin[((size_t)1 * BATCH + gb0 + b) * HIDDEN + gc];
  }

  for (int t = 0; t < SEQ; ++t) {
    if (t > 0) {
      unsigned int* bp = gbase + (size_t)(t & 1) * 131072;
      const unsigned want = (unsigned)t;
      uintx4 q0, q1, q2, q3, q4, q5, q6, q7;
      for (;;) {
        // fused issue+wait: no load outlives its asm statement (R5 lesson)
        asm volatile(
            "global_load_dwordx4 %0, %8, off sc1\n\t"
            "global_load_dwordx4 %1, %9, off sc1\n\t"
            "global_load_dwordx4 %2, %10, off sc1\n\t"
            "global_load_dwordx4 %3, %11, off sc1\n\t"
            "global_load_dwordx4 %4, %12, off sc1\n\t"
            "global_load_dwordx4 %5, %13, off sc1\n\t"
            "global_load_dwordx4 %6, %14, off sc1\n\t"
            "global_load_dwordx4 %7, %15, off sc1\n\t"
            "s_waitcnt vmcnt(0)"
            : "=&v"(q0), "=&v"(q1), "=&v"(q2), "=&v"(q3),
              "=&v"(q4), "=&v"(q5), "=&v"(q6), "=&v"(q7)
            : "v"(bp), "v"(bp + 2048), "v"(bp + 4096), "v"(bp + 6144),
              "v"(bp + 8192), "v"(bp + 10240), "v"(bp + 12288),
              "v"(bp + 14336)
            : "memory");
        unsigned bad = 0;
#define CH(Q) bad |= ((Q[0] ^ want) | (Q[1] ^ want) | (Q[2] ^ want) | \
                      (Q[3] ^ want)) & 0xFFFFu;
        CH(q0) CH(q1) CH(q2) CH(q3) CH(q4) CH(q5) CH(q6) CH(q7)
#undef CH
        if (!__any((int)(bad != 0u))) break;
      }
#define STRIP(Q, I)                                                          \
      {                                                                      \
        unsigned lo = __builtin_amdgcn_perm(Q[1], Q[0], 0x07060302u);        \
        unsigned hi = __builtin_amdgcn_perm(Q[3], Q[2], 0x07060302u);        \
        unsigned int* d =                                                    \
            reinterpret_cast<unsigned int*>(&Ald[2 * I + srow][scol4]);      \
        d[0] = lo; d[1] = hi;                                                \
      }
      STRIP(q0, 0) STRIP(q1, 1) STRIP(q2, 2) STRIP(q3, 3)
      STRIP(q4, 4) STRIP(q5, 5) STRIP(q6, 6) STRIP(q7, 7)
#undef STRIP
    }

    // xin loads for t+2 (issued here; consumed a full step later)
    {
      const int ts = (t + 2 < SEQ) ? t + 2 : SEQ - 1;
      xn[0] = xin[((size_t)ts * BATCH + gb0) * HIDDEN + gc];
      xn[1] = xin[((size_t)ts * BATCH + gb0 + 1) * HIDDEN + gc];
    }
    __syncthreads();  // B1: h_t staged in LDS

    floatx4 acc0 = (floatx4){0.f, 0.f, 0.f, 0.f};
    floatx4 acc1 = (floatx4){0.f, 0.f, 0.f, 0.f};
    if (t > 0) {
      const int kb = kg * 256 + lk;
#pragma unroll
      for (int kt = 0; kt < 8; ++kt) {
        half8 a = *reinterpret_cast<const half8*>(&Ald[l15][kb + kt * 32]);
        acc0 = __builtin_amdgcn_mfma_f32_16x16x32_f16(a, wf0[kt], acc0, 0, 0, 0);
        acc1 = __builtin_amdgcn_mfma_f32_16x16x32_f16(a, wf1[kt], acc1, 0, 0, 0);
      }
    }
    // publish K-quarter partials (kg-slot rotated; readers sum all 4)
    {
      const int slot = (kg + (l >> 3)) & 3;
#pragma unroll
      for (int i = 0; i < 4; ++i) {
        part[g][0][i][l][slot] = acc0[i];
        part[g][1][i][l][slot] = acc1[i];
      }
    }
    __syncthreads();  // B2: partials visible; also protects Ald WAR

    unsigned int* outb = hbuf + (size_t)((t + 1) & 1) * 131072 + m * 16384;
#pragma unroll
    for (int b = 0; b < 2; ++b) {
      const floatx4 p = *reinterpret_cast<const floatx4*>(
          &part[ntg][nt2][b ? i_1 : i_0][b ? lsrc1 : lsrc0][0]);
      const float s = (p[0] + p[1]) + (p[2] + p[3]);
      float pre = s + (float)xc[b] + bias_c;
      pre = fminf(fmaxf(pre, -15.f), 15.f);
      const float e = __expf(2.f * pre);
      const float dx = (e - 1.f) / (e + 1.f);
      const float hn = hown[b] + (dx - hown[b]) * invtau_c;
      hown[b] = hn;
      if (t < SEQ - 1) {
        const unsigned short hb =
            __builtin_bit_cast(unsigned short, (_Float16)hn);
        const unsigned word = ((unsigned)hb << 16) | (unsigned)(t + 1);
        __hip_atomic_store(outb + (r0 + b) * 1024 + gc, word,
                           __ATOMIC_RELAXED, __HIP_MEMORY_SCOPE_AGENT);
      } else {
        hfinal[(size_t)(gb0 + b) * HIDDEN + gc] = hn;
      }
    }
    // rotate xin pipeline
    xc[0] = x1[0]; xc[1] = x1[1];
    x1[0] = xn[0]; x1[1] = xn[1];
  }
}

// ---------------------------------------------------------------------------
// K3: out[B][256] = hfinal @ W_out + b_out
// ---------------------------------------------------------------------------
__global__ __launch_bounds__(256) void out_gemm(
    const float* __restrict__ hfinal, const float* __restrict__ Wout,
    const float* __restrict__ bout, float* __restrict__ out) {
  int b0 = blockIdx.x * 2;
  int o = threadIdx.x;
  float a0 = 0.f, a1 = 0.f;
  for (int k = 0; k < HIDDEN; ++k) {
    float wv = Wout[(size_t)k * OUTPUT + o];
    a0 += hfinal[(size_t)b0 * HIDDEN + k] * wv;
    a1 += hfinal[(size_t)(b0 + 1) * HIDDEN + k] * wv;
  }
  out[(size_t)b0 * OUTPUT + o] = a0 + bout[o];
  out[(size_t)(b0 + 1) * OUTPUT + o] = a1 + bout[o];
}

// ---------------------------------------------------------------------------
extern "C" void kernel_launch(void* const* d_in, const int* in_sizes, int n_in,
                              void* d_out, int out_size, void* d_ws,
                              size_t ws_size, hipStream_t stream) {
  const float* x     = (const float*)d_in[0];
  const float* W_in  = (const float*)d_in[1];
  const float* b_in  = (const float*)d_in[2];
  const float* W_h   = (const float*)d_in[3];
  const float* b_h   = (const float*)d_in[4];
  const float* tau   = (const float*)d_in[5];
  const float* W_out = (const float*)d_in[6];
  const float* b_out = (const float*)d_in[7];
  float* out = (float*)d_out;

  char* ws = (char*)d_ws;
  _Float16* xin = (_Float16*)ws;  ws += (size_t)BATCH * SEQ * HIDDEN * 2;  // 134MB
  _Float16* WinP = (_Float16*)ws; ws += (size_t)INPUT * HIDDEN * 2;        // 1MB
  _Float16* WhT = (_Float16*)ws;  ws += (size_t)HIDDEN * HIDDEN * 2;       // 2MB
  unsigned int* hbuf = (unsigned int*)ws;
  ws += (size_t)2 * BATCH * HIDDEN * 4;                                    // 1MB
  float* hfin = (float*)ws;       ws += (size_t)BATCH * HIDDEN * 4;        // 512KB

  // zero tags (tag 0 never polled: t=0 skips poll/MFMA since h_0 = 0)
  hipMemsetAsync(hbuf, 0, (size_t)2 * BATCH * HIDDEN * 4, stream);

  transpose_f32_to_f16<<<dim3(HIDDEN / 32, HIDDEN / 32), 256, 0, stream>>>(
      W_h, WhT, HIDDEN, HIDDEN);
  pack_win<<<(INPUT * HIDDEN) / 256, 256, 0, stream>>>(W_in, WinP);

  xin_gemm<<<(BATCH * SEQ / 64) * (HIDDEN / 128), 256, 0, stream>>>(x, WinP,
                                                                    xin);

  liquid_scan<<<128, 512, 0, stream>>>(xin, WhT, b_in, b_h, tau, hbuf, hfin);

  out_gemm<<<BATCH / 2, OUTPUT, 0, stream>>>(hfin, W_out, b_out, out);
}